// Round 9
// baseline (265.271 us; speedup 1.0000x reference)
//
#include <hip/hip_runtime.h>
#include <hip/hip_fp16.h>
#include <math.h>

// ---------------------------------------------------------------------------
// VariationalGCNEncoder: N=50000, E=800000, 128 -> 64 -> {32,32}
// R9: feature-split gathers. h arrays split into lo/hi 3.2MB halves so each
//     gather pass's random working set FITS the 4MB per-XCD L2 (R4-R8
//     evidence: 6.4MB array -> 35MB HBM FETCH, ~2.5TB/s effective, 40us).
//     Each edge now touches ONE 64B line. Quarter-wave per edge (16 lanes x
//     bf16x2), 4 edges/step, 16 in flight. gather2 = passA (g_lo rows to ws)
//     + passB (hi gather + coalesced g_lo reload + fused [Wmu|Wls] dot).
//     Skeleton reverted to R7's proven arrangement: [count|gemm(x f32)]
//     fused, fill standalone.
// Pipeline:
//   memset(counts) -> [count | gemm -> h_lo,h_hi] -> scan1 -> scan23 -> fill
//   gather1_lo, gather1_hi : h' = relu(A.h_pre + b1)     (bf16x2, split)
//   gather2a: g_lo = (A.h'_lo) rows (f32)                 (ws)
//   gather2b: out = [g_lo | A.h'_hi] @ [Wmu|Wls] + bias   (f32)
// ---------------------------------------------------------------------------

typedef unsigned int uint;
typedef unsigned short ushort;
typedef __attribute__((ext_vector_type(8))) short short8;   // 8 bf16 = 4 VGPR
typedef __attribute__((ext_vector_type(4))) float f32x4;    // MFMA acc
typedef __attribute__((ext_vector_type(2))) float f32v2;    // pk-fma pair

__device__ __forceinline__ ushort f2bf(float x) {          // f32 -> bf16 RNE
    uint u = __float_as_uint(x);
    u += 0x7fffu + ((u >> 16) & 1u);
    return (ushort)(u >> 16);
}
__device__ __forceinline__ float bf2f(ushort h) {
    return __uint_as_float((uint)h << 16);
}
__device__ __forceinline__ float unpack_norm(uint r) {     // fp16 in high 16
    return __half2float(__ushort_as_half((ushort)(r >> 16)));
}

// blocks [0,GB): MFMA gemm (h split lo/hi); blocks [GB,..): degree count
__global__ __launch_bounds__(256, 4) void k_count_gemm(
        const float* __restrict__ x, const float* __restrict__ W1,
        ushort* __restrict__ h_lo, ushort* __restrict__ h_hi, int N, int GB,
        const int* __restrict__ dst, int* __restrict__ counts, int E) {
    const int tid = threadIdx.x;
    if (blockIdx.x >= GB) {                        // ---- degree count ----
        int i = (blockIdx.x - GB) * 256 + tid;
        if (i < E) atomicAdd(&counts[dst[i]], 1);
        return;
    }
    // ---- MFMA gemm: wave = 16 rows x 64 cols, k=128 in 4 chunks ----
    const int w = tid >> 6, l = tid & 63;
    const int m = l & 15, q = l >> 4;              // q = quad (0..3)
    const int row0 = blockIdx.x * 64 + w * 16;
    const size_t arow = (size_t)min(row0 + m, N - 1);   // clamp; store guarded
    f32x4 acc0 = {0.f, 0.f, 0.f, 0.f}, acc1 = acc0, acc2 = acc0, acc3 = acc0;
    #pragma unroll
    for (int kc = 0; kc < 4; ++kc) {
        const int kofs = kc * 32 + q * 8;
        const float4* xr = (const float4*)(x + arow * 128 + kofs);
        float4 xa = xr[0], xb = xr[1];
        short8 a;
        a[0] = (short)f2bf(xa.x); a[1] = (short)f2bf(xa.y);
        a[2] = (short)f2bf(xa.z); a[3] = (short)f2bf(xa.w);
        a[4] = (short)f2bf(xb.x); a[5] = (short)f2bf(xb.y);
        a[6] = (short)f2bf(xb.z); a[7] = (short)f2bf(xb.w);
        short8 b0, b1, b2, b3;                     // W1 L1-hot (32 KB)
        #pragma unroll
        for (int i = 0; i < 8; ++i) {
            const float* wk = W1 + (size_t)(kofs + i) * 64 + m;
            b0[i] = (short)f2bf(wk[0]);
            b1[i] = (short)f2bf(wk[16]);
            b2[i] = (short)f2bf(wk[32]);
            b3[i] = (short)f2bf(wk[48]);
        }
        acc0 = __builtin_amdgcn_mfma_f32_16x16x32_bf16(a, b0, acc0, 0, 0, 0);
        acc1 = __builtin_amdgcn_mfma_f32_16x16x32_bf16(a, b1, acc1, 0, 0, 0);
        acc2 = __builtin_amdgcn_mfma_f32_16x16x32_bf16(a, b2, acc2, 0, 0, 0);
        acc3 = __builtin_amdgcn_mfma_f32_16x16x32_bf16(a, b3, acc3, 0, 0, 0);
    }
    #pragma unroll
    for (int r = 0; r < 4; ++r) {                  // D: row=q*4+r, col=g*16+m
        int row = row0 + q * 4 + r;
        if (row >= N) continue;
        ushort* lo = h_lo + (size_t)row * 32 + m;  // cols 0..31
        lo[0]  = f2bf(acc0[r]);
        lo[16] = f2bf(acc1[r]);
        ushort* hi = h_hi + (size_t)row * 32 + m;  // cols 32..63
        hi[0]  = f2bf(acc2[r]);
        hi[16] = f2bf(acc3[r]);
    }
}

// per-block exclusive scan of counts -> row_ptr, block sums -> bsum
__global__ __launch_bounds__(256) void k_scan1(const int* __restrict__ counts,
                                               int* __restrict__ row_ptr,
                                               int* __restrict__ bsum, int N) {
    __shared__ int s[256];
    int t = threadIdx.x, i = blockIdx.x * 256 + t;
    int v = (i < N) ? counts[i] : 0;
    s[t] = v;
    __syncthreads();
    #pragma unroll
    for (int off = 1; off < 256; off <<= 1) {
        int x = (t >= off) ? s[t - off] : 0;
        __syncthreads();
        s[t] += x;
        __syncthreads();
    }
    if (i < N) row_ptr[i] = s[t] - v;
    if (t == 255) bsum[blockIdx.x] = s[255];
}

// fused scan2+scan3 (NB<=256)
__global__ __launch_bounds__(256) void k_scan23(
        int* __restrict__ row_ptr, const int* __restrict__ bsum,
        const int* __restrict__ counts, int* __restrict__ cursor,
        float* __restrict__ dinv, int N, int E, int NB) {
    __shared__ int s[256];
    const int t = threadIdx.x;
    s[t] = (t < blockIdx.x && t < NB) ? bsum[t] : 0;
    __syncthreads();
    #pragma unroll
    for (int off = 128; off >= 1; off >>= 1) {
        if (t < off) s[t] += s[t + off];
        __syncthreads();
    }
    const int offset = s[0];
    const int i = blockIdx.x * 256 + t;
    if (i < N) {
        int r = row_ptr[i] + offset;
        row_ptr[i] = r;
        cursor[i] = r;
        dinv[i] = rsqrtf((float)(counts[i] + 1));
    }
    if (blockIdx.x == 0 && t == 0) row_ptr[N] = E;
}

// packed edge record: low 16 = src (N < 65536), high 16 = fp16(norm)
__global__ __launch_bounds__(256) void k_fill(
        const int* __restrict__ src, const int* __restrict__ dst,
        const float* __restrict__ dinv, int* __restrict__ cursor,
        uint* __restrict__ edges, int E) {
    int e = blockIdx.x * blockDim.x + threadIdx.x;
    if (e >= E) return;
    int s = src[e], d = dst[e];
    int pos = atomicAdd(&cursor[d], 1);
    ushort nb = __half_as_ushort(__float2half(dinv[s] * dinv[d]));
    edges[pos] = (uint)s | ((uint)nb << 16);
}

// Gather over ONE 32-feature half. Quarter-wave per edge: lane = (q, hl),
// q in 0..3 picks edge-within-step, hl in 0..15 picks bf16x2 feature pair.
// 4 edges/step, 4-step unroll = 16 edges in flight. After the loop, the
// butterfly reduce sums the 4 quarters; all lanes end with the full row sum.
__device__ __forceinline__ f32v2 gather_half(
        const uint* __restrict__ hp, const uint* __restrict__ edges,
        int beg, int end, int E, int lane, int hl, int q) {
    f32v2 acc = {0.f, 0.f};
    for (int base = beg; base < end; base += 64) {
        int cnt = end - base; if (cnt > 64) cnt = 64;
        uint mrec = edges[min(base + lane, E - 1)];
        int steps = (cnt + 3) >> 2;
        for (int t = 0; t < steps; t += 4) {
            if (4 * t + 16 <= cnt) {      // edges 4t..4t+15 all valid
                #pragma unroll
                for (int i = 0; i < 4; ++i) {
                    uint r = __shfl(mrec, 4 * (t + i) + q);
                    uint v = hp[(size_t)(r & 0xffffu) * 16 + hl];
                    float wn = unpack_norm(r);
                    f32v2 vf;
                    vf.x = __uint_as_float(v << 16);
                    vf.y = __uint_as_float(v & 0xffff0000u);
                    acc = vf * wn + acc;
                }
            } else {
                #pragma unroll
                for (int i = 0; i < 4; ++i) {
                    int e = 4 * (t + i) + q;
                    uint r = __shfl(mrec, min(e, cnt - 1));
                    uint v = hp[(size_t)(r & 0xffffu) * 16 + hl];
                    float wn = (e < cnt) ? unpack_norm(r) : 0.f;
                    f32v2 vf;
                    vf.x = __uint_as_float(v << 16);
                    vf.y = __uint_as_float(v & 0xffff0000u);
                    acc = vf * wn + acc;
                }
            }
        }
    }
    acc.x += __shfl_xor(acc.x, 16); acc.x += __shfl_xor(acc.x, 32);
    acc.y += __shfl_xor(acc.y, 16); acc.y += __shfl_xor(acc.y, 32);
    return acc;
}

// one feature-half of layer 1: h'[n] = relu(dinv^2*hp[n] + b1h + sum norm*hp[src])
__global__ __launch_bounds__(256, 8) void k_gather1(
        const uint* __restrict__ hp, const int* __restrict__ row_ptr,
        const uint* __restrict__ edges, const float* __restrict__ dinv,
        const float* __restrict__ b1h, uint* __restrict__ ho, int N, int E) {
    const int lane = threadIdx.x & 63;
    const int hl = lane & 15, q = lane >> 4;
    const int n = blockIdx.x * 4 + (threadIdx.x >> 6);
    if (n >= N) return;
    const int beg = row_ptr[n], end = row_ptr[n + 1];
    f32v2 acc = gather_half(hp, edges, beg, end, E, lane, hl, q);
    const float dv = dinv[n];
    const uint sv = hp[(size_t)n * 16 + hl];
    const float2 b = ((const float2*)b1h)[hl];
    acc.x += dv * dv * bf2f((ushort)sv) + b.x;
    acc.y += dv * dv * bf2f((ushort)(sv >> 16)) + b.y;
    if (q == 0) {
        uint p = (uint)f2bf(fmaxf(acc.x, 0.f)) | ((uint)f2bf(fmaxf(acc.y, 0.f)) << 16);
        ho[(size_t)n * 16 + hl] = p;
    }
}

// layer-2 pass A: g_lo[n][0..31] = (A_norm . h'_lo + self) rows, f32 to ws
__global__ __launch_bounds__(256, 8) void k_gather2a(
        const uint* __restrict__ hp, const int* __restrict__ row_ptr,
        const uint* __restrict__ edges, const float* __restrict__ dinv,
        float* __restrict__ glo, int N, int E) {
    const int lane = threadIdx.x & 63;
    const int hl = lane & 15, q = lane >> 4;
    const int n = blockIdx.x * 4 + (threadIdx.x >> 6);
    if (n >= N) return;
    const int beg = row_ptr[n], end = row_ptr[n + 1];
    f32v2 acc = gather_half(hp, edges, beg, end, E, lane, hl, q);
    const float dv = dinv[n];
    const uint sv = hp[(size_t)n * 16 + hl];
    acc.x += dv * dv * bf2f((ushort)sv);
    acc.y += dv * dv * bf2f((ushort)(sv >> 16));
    if (q == 0) {
        float2 p; p.x = acc.x; p.y = acc.y;
        ((float2*)(glo + (size_t)n * 32))[hl] = p;
    }
}

// layer-2 pass B: g_hi gather + coalesced g_lo reload -> full 64-dim g row
// -> out[n] = g @ [Wmu|Wls] + bias
__global__ __launch_bounds__(256, 8) void k_gather2b(
        const uint* __restrict__ hp, const float* __restrict__ glo,
        const int* __restrict__ row_ptr, const uint* __restrict__ edges,
        const float* __restrict__ dinv,
        const float* __restrict__ Wmu, const float* __restrict__ Wls,
        const float* __restrict__ bmu, const float* __restrict__ bls,
        float* __restrict__ out, int N, int E) {
    __shared__ float hs[4][64];    // per-wave full g row (1 KB)
    const int lane = threadIdx.x & 63;
    const int hl = lane & 15, q = lane >> 4;
    const int w = threadIdx.x >> 6;
    const int n = blockIdx.x * 4 + w;
    if (n >= N) return;
    const int beg = row_ptr[n], end = row_ptr[n + 1];
    f32v2 acc = gather_half(hp, edges, beg, end, E, lane, hl, q);
    const float dv = dinv[n];
    const uint sv = hp[(size_t)n * 16 + hl];
    acc.x += dv * dv * bf2f((ushort)sv);
    acc.y += dv * dv * bf2f((ushort)(sv >> 16));
    if (q == 0) {                                   // stage g row in LDS
        float2 gv = ((const float2*)(glo + (size_t)n * 32))[hl];
        *(float2*)&hs[w][2 * hl] = gv;              // g[0..31]
        float2 p; p.x = acc.x; p.y = acc.y;
        *(float2*)&hs[w][32 + 2 * hl] = p;          // g[32..63]
    }
    // epilogue: out_row = g @ [Wmu|Wls] + bias ; W from global (L1-hot)
    const float* Wsel = (lane < 32) ? (Wmu + lane) : (Wls + (lane - 32));
    const float bias  = (lane < 32) ? bmu[lane] : bls[lane - 32];
    float c0 = 0.f, c1 = 0.f, c2 = 0.f, c3 = 0.f;
    #pragma unroll 4
    for (int k = 0; k < 64; k += 4) {
        c0 = fmaf(hs[w][k + 0], Wsel[(k + 0) * 32], c0);
        c1 = fmaf(hs[w][k + 1], Wsel[(k + 1) * 32], c1);
        c2 = fmaf(hs[w][k + 2], Wsel[(k + 2) * 32], c2);
        c3 = fmaf(hs[w][k + 3], Wsel[(k + 3) * 32], c3);
    }
    float t = (c0 + c1) + (c2 + c3) + bias;
    if (lane < 32) out[(size_t)n * 32 + lane] = t;
    else           out[(size_t)N * 32 + (size_t)n * 32 + (lane - 32)] = t;
}

extern "C" void kernel_launch(void* const* d_in, const int* in_sizes, int n_in,
                              void* d_out, int out_size, void* d_ws, size_t ws_size,
                              hipStream_t stream) {
    const float* x   = (const float*)d_in[0];
    const int*   ei  = (const int*)d_in[1];
    const float* W1  = (const float*)d_in[2];
    const float* b1  = (const float*)d_in[3];
    const float* Wmu = (const float*)d_in[4];
    const float* bmu = (const float*)d_in[5];
    const float* Wls = (const float*)d_in[6];
    const float* bls = (const float*)d_in[7];
    float* out = (float*)d_out;

    const int N = in_sizes[0] / 128;          // 50000  (< 65536: u16 src pack)
    const int E = in_sizes[1] / 2;            // 800000
    const int* src = ei;
    const int* dst = ei + E;
    const int NB = (N + 255) / 256;           // scan blocks (196 <= 256)
    const int CB = (E + 255) / 256;           // count / fill blocks
    const int GB = (N + 63) / 64;             // gemm row-tile blocks
    const int NG = (N + 3) / 4;               // gather blocks

    char* w = (char*)d_ws;
    auto carve = [&](size_t bytes) { char* p = w; w += (bytes + 1023) & ~(size_t)1023; return p; };
    int*    counts  = (int*)   carve((size_t)N * 4);
    int*    row_ptr = (int*)   carve((size_t)(N + 1) * 4);
    int*    cursor  = (int*)   carve((size_t)N * 4);
    int*    bsum    = (int*)   carve(256 * 4);
    float*  dinv    = (float*) carve((size_t)N * 4);
    uint*   edges   = (uint*)  carve((size_t)E * 4);
    ushort* hp_lo   = (ushort*)carve((size_t)N * 32 * 2);   // h_pre cols 0..31
    ushort* hp_hi   = (ushort*)carve((size_t)N * 32 * 2);   // h_pre cols 32..63
    ushort* hm_lo   = (ushort*)carve((size_t)N * 32 * 2);   // h' cols 0..31
    ushort* hm_hi   = (ushort*)carve((size_t)N * 32 * 2);   // h' cols 32..63
    float*  glo     = (float*) carve((size_t)N * 32 * 4);   // layer-2 lo rows

    hipMemsetAsync(counts, 0, (size_t)N * 4, stream);
    k_count_gemm<<<GB + CB, 256, 0, stream>>>(x, W1, hp_lo, hp_hi, N, GB, dst, counts, E);
    k_scan1     <<<NB, 256, 0, stream>>>(counts, row_ptr, bsum, N);
    k_scan23    <<<NB, 256, 0, stream>>>(row_ptr, bsum, counts, cursor, dinv, N, E, NB);
    k_fill      <<<CB, 256, 0, stream>>>(src, dst, dinv, cursor, edges, E);
    k_gather1   <<<NG, 256, 0, stream>>>((const uint*)hp_lo, row_ptr, edges, dinv,
                                         b1,      (uint*)hm_lo, N, E);
    k_gather1   <<<NG, 256, 0, stream>>>((const uint*)hp_hi, row_ptr, edges, dinv,
                                         b1 + 32, (uint*)hm_hi, N, E);
    k_gather2a  <<<NG, 256, 0, stream>>>((const uint*)hm_lo, row_ptr, edges, dinv,
                                         glo, N, E);
    k_gather2b  <<<NG, 256, 0, stream>>>((const uint*)hm_hi, glo, row_ptr, edges, dinv,
                                         Wmu, Wls, bmu, bls, out, N, E);
}

// Round 10
// 229.844 us; speedup vs baseline: 1.1541x; 1.1541x over previous
//
#include <hip/hip_runtime.h>
#include <hip/hip_fp16.h>
#include <math.h>

// ---------------------------------------------------------------------------
// VariationalGCNEncoder: N=50000, E=800000, 128 -> 64 -> {32,32}
// R10: R7 skeleton + norm-folding. A.h = dinv[d]*(sum_e dinv[s]h[s] + dinv[d]h[d])
//      -> store node rows PRE-SCALED by dinv; edge record = u16 src only
//      (1.6MB); gather inner loop = pure pk-adds (no per-edge norm).
//      Non-temporal src/dst streams in fill/count keep dirty edge lines L2-
//      resident (R9 evidence: 55MB line-granular writeback from 4B scatters).
// Pipeline:
//   memset(counts) -> [gemm h_pre | count(nt)] -> scan1 -> scan23
//   [fill(u16, nt) | hp *= dinv[row]]
//   gather1: hm = dinv * relu(dinv * (sum hp_s[src] + hp_s[n]) + b1)   bf16
//   gather2: out = dinv*(sum hm[src] + hm[n]) @ [Wmu|Wls] + bias       f32
// ---------------------------------------------------------------------------

typedef unsigned int uint;
typedef unsigned short ushort;
typedef __attribute__((ext_vector_type(8))) short short8;   // 8 bf16 = 4 VGPR
typedef __attribute__((ext_vector_type(4))) float f32x4;    // MFMA acc
typedef __attribute__((ext_vector_type(2))) float f32v2;    // pk pair

__device__ __forceinline__ ushort f2bf(float x) {          // f32 -> bf16 RNE
    uint u = __float_as_uint(x);
    u += 0x7fffu + ((u >> 16) & 1u);
    return (ushort)(u >> 16);
}
__device__ __forceinline__ float bf2f(ushort h) {
    return __uint_as_float((uint)h << 16);
}

// blocks [0,GB): MFMA gemm h_pre = bf16(x) @ bf16(W1); blocks [GB,..): count
__global__ __launch_bounds__(256, 4) void k_count_gemm(
        const float* __restrict__ x, const float* __restrict__ W1,
        ushort* __restrict__ h_pre, int N, int GB,
        const int* __restrict__ dst, int* __restrict__ counts, int E) {
    const int tid = threadIdx.x;
    if (blockIdx.x >= GB) {                        // ---- degree count ----
        int i = (blockIdx.x - GB) * 256 + tid;
        if (i < E) {
            int d = __builtin_nontemporal_load(dst + i);
            atomicAdd(&counts[d], 1);
        }
        return;
    }
    // ---- MFMA gemm: wave = 16 rows x 64 cols, k=128 in 4 chunks ----
    const int w = tid >> 6, l = tid & 63;
    const int m = l & 15, q = l >> 4;              // q = quad (0..3)
    const int row0 = blockIdx.x * 64 + w * 16;
    const size_t arow = (size_t)min(row0 + m, N - 1);   // clamp; store guarded
    f32x4 acc0 = {0.f, 0.f, 0.f, 0.f}, acc1 = acc0, acc2 = acc0, acc3 = acc0;
    #pragma unroll
    for (int kc = 0; kc < 4; ++kc) {
        const int kofs = kc * 32 + q * 8;
        const float4* xr = (const float4*)(x + arow * 128 + kofs);
        float4 xa = xr[0], xb = xr[1];
        short8 a;
        a[0] = (short)f2bf(xa.x); a[1] = (short)f2bf(xa.y);
        a[2] = (short)f2bf(xa.z); a[3] = (short)f2bf(xa.w);
        a[4] = (short)f2bf(xb.x); a[5] = (short)f2bf(xb.y);
        a[6] = (short)f2bf(xb.z); a[7] = (short)f2bf(xb.w);
        short8 b0, b1, b2, b3;                     // W1 L1-hot (32 KB)
        #pragma unroll
        for (int i = 0; i < 8; ++i) {
            const float* wk = W1 + (size_t)(kofs + i) * 64 + m;
            b0[i] = (short)f2bf(wk[0]);
            b1[i] = (short)f2bf(wk[16]);
            b2[i] = (short)f2bf(wk[32]);
            b3[i] = (short)f2bf(wk[48]);
        }
        acc0 = __builtin_amdgcn_mfma_f32_16x16x32_bf16(a, b0, acc0, 0, 0, 0);
        acc1 = __builtin_amdgcn_mfma_f32_16x16x32_bf16(a, b1, acc1, 0, 0, 0);
        acc2 = __builtin_amdgcn_mfma_f32_16x16x32_bf16(a, b2, acc2, 0, 0, 0);
        acc3 = __builtin_amdgcn_mfma_f32_16x16x32_bf16(a, b3, acc3, 0, 0, 0);
    }
    #pragma unroll
    for (int r = 0; r < 4; ++r) {                  // D: row=q*4+r, col=g*16+m
        int row = row0 + q * 4 + r;
        if (row >= N) continue;
        ushort* hr = h_pre + (size_t)row * 64 + m;
        hr[0]  = f2bf(acc0[r]);
        hr[16] = f2bf(acc1[r]);
        hr[32] = f2bf(acc2[r]);
        hr[48] = f2bf(acc3[r]);
    }
}

// per-block exclusive scan of counts -> row_ptr, block sums -> bsum
__global__ __launch_bounds__(256) void k_scan1(const int* __restrict__ counts,
                                               int* __restrict__ row_ptr,
                                               int* __restrict__ bsum, int N) {
    __shared__ int s[256];
    int t = threadIdx.x, i = blockIdx.x * 256 + t;
    int v = (i < N) ? counts[i] : 0;
    s[t] = v;
    __syncthreads();
    #pragma unroll
    for (int off = 1; off < 256; off <<= 1) {
        int x = (t >= off) ? s[t - off] : 0;
        __syncthreads();
        s[t] += x;
        __syncthreads();
    }
    if (i < N) row_ptr[i] = s[t] - v;
    if (t == 255) bsum[blockIdx.x] = s[255];
}

// fused scan2+scan3 (NB<=256)
__global__ __launch_bounds__(256) void k_scan23(
        int* __restrict__ row_ptr, const int* __restrict__ bsum,
        const int* __restrict__ counts, int* __restrict__ cursor,
        float* __restrict__ dinv, int N, int E, int NB) {
    __shared__ int s[256];
    const int t = threadIdx.x;
    s[t] = (t < blockIdx.x && t < NB) ? bsum[t] : 0;
    __syncthreads();
    #pragma unroll
    for (int off = 128; off >= 1; off >>= 1) {
        if (t < off) s[t] += s[t + off];
        __syncthreads();
    }
    const int offset = s[0];
    const int i = blockIdx.x * 256 + t;
    if (i < N) {
        int r = row_ptr[i] + offset;
        row_ptr[i] = r;
        cursor[i] = r;
        dinv[i] = rsqrtf((float)(counts[i] + 1));
    }
    if (blockIdx.x == 0 && t == 0) row_ptr[N] = E;
}

// blocks [0,FB): CSR fill, u16 src records, nt streams (keeps dirty edge
// lines L2-resident). blocks [FB,..): hp[j] *= dinv[row] in place (coalesced).
__global__ __launch_bounds__(256) void k_fill_scale(
        const int* __restrict__ src, const int* __restrict__ dst,
        const float* __restrict__ dinv, int* __restrict__ cursor,
        ushort* __restrict__ edges, int E, int FB,
        uint* __restrict__ hp, int N) {
    const int tid = threadIdx.x;
    if (blockIdx.x < FB) {                         // ---- CSR fill ----
        int e = blockIdx.x * 256 + tid;
        if (e >= E) return;
        int s = __builtin_nontemporal_load(src + e);
        int d = __builtin_nontemporal_load(dst + e);
        int pos = atomicAdd(&cursor[d], 1);
        edges[pos] = (ushort)s;
        return;
    }
    int j = (blockIdx.x - FB) * 256 + tid;         // ---- hp *= dinv ----
    if (j >= N * 32) return;
    float dv = dinv[j >> 5];
    uint v = hp[j];
    float lo = bf2f((ushort)v) * dv;
    float hi = bf2f((ushort)(v >> 16)) * dv;
    hp[j] = (uint)f2bf(lo) | ((uint)f2bf(hi) << 16);
}

// Norm-free gather over 64-feature rows (32 uints). Half-wave per edge:
// hl = lane&31 (feature pair), half = lane>>5 (edge parity). 2 edges/step,
// 8-step unroll = 16 row-loads in flight. Pure pk-adds. Butterfly at end.
__device__ __forceinline__ f32v2 gather_rows(
        const uint* __restrict__ hp, const ushort* __restrict__ edges,
        int beg, int end, int E, int lane, int hl, int half) {
    f32v2 acc = {0.f, 0.f};
    for (int base = beg; base < end; base += 64) {
        int cnt = end - base; if (cnt > 64) cnt = 64;
        int mrec = (int)edges[min(base + lane, E - 1)];   // coalesced 2B/lane
        int steps = (cnt + 1) >> 1;
        for (int t = 0; t < steps; t += 8) {
            if (2 * t + 16 <= cnt) {       // edges 2t..2t+15 all valid
                #pragma unroll
                for (int i = 0; i < 8; ++i) {
                    int r = __shfl(mrec, 2 * (t + i) + half);
                    uint v = hp[(size_t)r * 32 + hl];
                    f32v2 vf;
                    vf.x = __uint_as_float(v << 16);
                    vf.y = __uint_as_float(v & 0xffff0000u);
                    acc = acc + vf;
                }
            } else {
                #pragma unroll
                for (int i = 0; i < 8; ++i) {
                    int e = 2 * (t + i) + half;
                    int r = __shfl(mrec, min(e, cnt - 1));
                    uint v = hp[(size_t)r * 32 + hl];
                    v = (e < cnt) ? v : 0u;
                    f32v2 vf;
                    vf.x = __uint_as_float(v << 16);
                    vf.y = __uint_as_float(v & 0xffff0000u);
                    acc = acc + vf;
                }
            }
        }
    }
    acc.x += __shfl_xor(acc.x, 32);
    acc.y += __shfl_xor(acc.y, 32);
    return acc;
}

// hm[n] = dinv * relu( dinv * (sum hp_s[src] + hp_s[n]) + b1 )   (bf16x2)
__global__ __launch_bounds__(256, 8) void k_gather1(
        const uint* __restrict__ hp, const int* __restrict__ row_ptr,
        const ushort* __restrict__ edges, const float* __restrict__ dinv,
        const float* __restrict__ b1, uint* __restrict__ ho, int N, int E) {
    const int lane = threadIdx.x & 63;
    const int hl = lane & 31, half = lane >> 5;
    const int n = blockIdx.x * 4 + (threadIdx.x >> 6);
    if (n >= N) return;
    const int beg = row_ptr[n], end = row_ptr[n + 1];
    f32v2 acc = gather_rows(hp, edges, beg, end, E, lane, hl, half);
    if (half == 0) {
        const float dv = dinv[n];
        const uint sv = hp[(size_t)n * 32 + hl];       // self (pre-scaled)
        const float2 b = ((const float2*)b1)[hl];
        float s0 = acc.x + bf2f((ushort)sv);
        float s1 = acc.y + bf2f((ushort)(sv >> 16));
        float h0 = fmaxf(fmaf(dv, s0, b.x), 0.f) * dv; // relu then pre-scale
        float h1 = fmaxf(fmaf(dv, s1, b.y), 0.f) * dv;
        ho[(size_t)n * 32 + hl] = (uint)f2bf(h0) | ((uint)f2bf(h1) << 16);
    }
}

// g = dinv*(sum hm[src] + hm[n]);  out[n] = g @ [Wmu|Wls] + bias
__global__ __launch_bounds__(256, 8) void k_gather2(
        const uint* __restrict__ hp, const int* __restrict__ row_ptr,
        const ushort* __restrict__ edges, const float* __restrict__ dinv,
        const float* __restrict__ Wmu, const float* __restrict__ Wls,
        const float* __restrict__ bmu, const float* __restrict__ bls,
        float* __restrict__ out, int N, int E) {
    __shared__ float hs[4][64];    // per-wave g row (1 KB)
    const int lane = threadIdx.x & 63;
    const int hl = lane & 31, half = lane >> 5;
    const int w = threadIdx.x >> 6;
    const int n = blockIdx.x * 4 + w;
    if (n >= N) return;
    const int beg = row_ptr[n], end = row_ptr[n + 1];
    f32v2 acc = gather_rows(hp, edges, beg, end, E, lane, hl, half);
    if (half == 0) {
        const float dv = dinv[n];
        const uint sv = hp[(size_t)n * 32 + hl];
        float g0 = dv * (acc.x + bf2f((ushort)sv));
        float g1 = dv * (acc.y + bf2f((ushort)(sv >> 16)));
        float2 p; p.x = g0; p.y = g1;
        *(float2*)&hs[w][2 * hl] = p;
    }
    // epilogue: out_row = g @ [Wmu|Wls] + bias ; W from global (L1-hot)
    const float* Wsel = (lane < 32) ? (Wmu + lane) : (Wls + (lane - 32));
    const float bias  = (lane < 32) ? bmu[lane] : bls[lane - 32];
    float c0 = 0.f, c1 = 0.f, c2 = 0.f, c3 = 0.f;
    #pragma unroll 4
    for (int k = 0; k < 64; k += 4) {
        c0 = fmaf(hs[w][k + 0], Wsel[(k + 0) * 32], c0);
        c1 = fmaf(hs[w][k + 1], Wsel[(k + 1) * 32], c1);
        c2 = fmaf(hs[w][k + 2], Wsel[(k + 2) * 32], c2);
        c3 = fmaf(hs[w][k + 3], Wsel[(k + 3) * 32], c3);
    }
    float t = (c0 + c1) + (c2 + c3) + bias;
    if (lane < 32) out[(size_t)n * 32 + lane] = t;
    else           out[(size_t)N * 32 + (size_t)n * 32 + (lane - 32)] = t;
}

extern "C" void kernel_launch(void* const* d_in, const int* in_sizes, int n_in,
                              void* d_out, int out_size, void* d_ws, size_t ws_size,
                              hipStream_t stream) {
    const float* x   = (const float*)d_in[0];
    const int*   ei  = (const int*)d_in[1];
    const float* W1  = (const float*)d_in[2];
    const float* b1  = (const float*)d_in[3];
    const float* Wmu = (const float*)d_in[4];
    const float* bmu = (const float*)d_in[5];
    const float* Wls = (const float*)d_in[6];
    const float* bls = (const float*)d_in[7];
    float* out = (float*)d_out;

    const int N = in_sizes[0] / 128;          // 50000  (< 65536: u16 src pack)
    const int E = in_sizes[1] / 2;            // 800000
    const int* src = ei;
    const int* dst = ei + E;
    const int NB = (N + 255) / 256;           // scan blocks (196 <= 256)
    const int CB = (E + 255) / 256;           // count / fill blocks
    const int GB = (N + 63) / 64;             // gemm row-tile blocks
    const int SB = (N * 32 + 255) / 256;      // hp-scale blocks
    const int NG = (N + 3) / 4;               // gather blocks

    char* w = (char*)d_ws;
    auto carve = [&](size_t bytes) { char* p = w; w += (bytes + 1023) & ~(size_t)1023; return p; };
    int*    counts  = (int*)   carve((size_t)N * 4);
    int*    row_ptr = (int*)   carve((size_t)(N + 1) * 4);
    int*    cursor  = (int*)   carve((size_t)N * 4);
    int*    bsum    = (int*)   carve(256 * 4);
    float*  dinv    = (float*) carve((size_t)N * 4);
    ushort* edges   = (ushort*)carve((size_t)E * 2);        // u16 src records
    ushort* h_pre   = (ushort*)carve((size_t)N * 64 * 2);   // bf16 (scaled in place)
    ushort* h_mid   = (ushort*)carve((size_t)N * 64 * 2);   // bf16 (pre-scaled)

    hipMemsetAsync(counts, 0, (size_t)N * 4, stream);
    k_count_gemm<<<GB + CB, 256, 0, stream>>>(x, W1, h_pre, N, GB, dst, counts, E);
    k_scan1     <<<NB, 256, 0, stream>>>(counts, row_ptr, bsum, N);
    k_scan23    <<<NB, 256, 0, stream>>>(row_ptr, bsum, counts, cursor, dinv, N, E, NB);
    k_fill_scale<<<CB + SB, 256, 0, stream>>>(src, dst, dinv, cursor, edges, E, CB,
                                              (uint*)h_pre, N);
    k_gather1   <<<NG, 256, 0, stream>>>((const uint*)h_pre, row_ptr, edges, dinv,
                                         b1, (uint*)h_mid, N, E);
    k_gather2   <<<NG, 256, 0, stream>>>((const uint*)h_mid, row_ptr, edges, dinv,
                                         Wmu, Wls, bmu, bls, out, N, E);
}

// Round 11
// 194.755 us; speedup vs baseline: 1.3621x; 1.1802x over previous
//
#include <hip/hip_runtime.h>
#include <hip/hip_fp16.h>
#include <math.h>

// ---------------------------------------------------------------------------
// VariationalGCNEncoder: N=50000, E=800000, 128 -> 64 -> {32,32}
// R11: CSR build rewritten as 2-level bucketed counting sort to kill the
//      cross-XCD line-bounce writeback (R10: 48MB WRITE for 1.6MB of edge
//      records). Coarse bucket = dst>>8 (196 buckets, 256 nodes, ~4K edges):
//        hist (LDS histogram, 1 atomic per block-bucket) -> bscan ->
//        scatterA (run-aggregated u32 records: ~10-record contiguous runs) ->
//        phaseB (1 block per bucket: row_ptr+dinv coalesced, u16 edge scatter
//        into an 8KB single-block-local region).
//      dinv-prescale of h_pre folded into the MFMA gemm epilogue (gemm now
//      runs after phaseB). Gathers = R10's norm-free pk-add core, unchanged.
// Pipeline:
//   memset(bcount) -> hist -> bscan -> scatterA -> phaseB
//   gemm: hp = dinv[row] * (bf16(x) @ bf16(W1))        bf16
//   gather1: hm = dinv * relu(dinv*(sum hp[src] + hp[n]) + b1)   bf16
//   gather2: out = dinv*(sum hm[src] + hm[n]) @ [Wmu|Wls] + bias f32
// ---------------------------------------------------------------------------

typedef unsigned int uint;
typedef unsigned short ushort;
typedef __attribute__((ext_vector_type(8))) short short8;   // 8 bf16 = 4 VGPR
typedef __attribute__((ext_vector_type(4))) float f32x4;    // MFMA acc
typedef __attribute__((ext_vector_type(2))) float f32v2;    // pk pair

__device__ __forceinline__ ushort f2bf(float x) {          // f32 -> bf16 RNE
    uint u = __float_as_uint(x);
    u += 0x7fffu + ((u >> 16) & 1u);
    return (ushort)(u >> 16);
}
__device__ __forceinline__ float bf2f(ushort h) {
    return __uint_as_float((uint)h << 16);
}

// ---- CSR build, level A: coarse histogram (2048 edges/block) ----
__global__ __launch_bounds__(256) void k_hist(
        const int* __restrict__ dst, int* __restrict__ bcount, int E) {
    __shared__ int h[256];
    const int tid = threadIdx.x;
    h[tid] = 0;
    __syncthreads();
    const int base = blockIdx.x * 2048;
    #pragma unroll
    for (int k = 0; k < 8; ++k) {
        int i = base + k * 256 + tid;
        if (i < E) {
            int d = __builtin_nontemporal_load(dst + i);
            atomicAdd(&h[d >> 8], 1);
        }
    }
    __syncthreads();
    if (h[tid]) atomicAdd(&bcount[tid], h[tid]);
}

// ---- bucket scan: bbase (excl prefix, bbase[256]=E), bcursor=bbase ----
__global__ __launch_bounds__(256) void k_bscan(
        const int* __restrict__ bcount, int* __restrict__ bbase,
        int* __restrict__ bcursor, int E) {
    __shared__ int p[256];
    const int t = threadIdx.x;
    int v = bcount[t];
    p[t] = v;
    __syncthreads();
    #pragma unroll
    for (int off = 1; off < 256; off <<= 1) {
        int x = (t >= off) ? p[t - off] : 0;
        __syncthreads();
        p[t] += x;
        __syncthreads();
    }
    int excl = p[t] - v;
    bbase[t] = excl;
    bcursor[t] = excl;
    if (t == 255) bbase[256] = p[255];   // == E
}

// ---- level A scatter: rec = src(16) | dstlow(8)<<16 | bucket(8)<<24 ----
// Per-block LDS rank + one cursor atomic per (block,bucket) -> contiguous
// ~10-record runs; L2 merges partial lines instead of bouncing per store.
__global__ __launch_bounds__(256) void k_scatterA(
        const int* __restrict__ src, const int* __restrict__ dst,
        int* __restrict__ bcursor, uint* __restrict__ recs, int E) {
    __shared__ int h[256];
    __shared__ int rb[256];
    const int tid = threadIdx.x;
    h[tid] = 0;
    __syncthreads();
    const int base = blockIdx.x * 2048;
    uint rec[8]; int rk[8];
    #pragma unroll
    for (int k = 0; k < 8; ++k) {
        int i = base + k * 256 + tid;
        if (i < E) {
            int s = __builtin_nontemporal_load(src + i);
            int d = __builtin_nontemporal_load(dst + i);
            int b = d >> 8;
            rec[k] = (uint)s | ((uint)(d & 255) << 16) | ((uint)b << 24);
            rk[k] = atomicAdd(&h[b], 1);
        }
    }
    __syncthreads();
    rb[tid] = h[tid] ? atomicAdd(&bcursor[tid], h[tid]) : 0;
    __syncthreads();
    #pragma unroll
    for (int k = 0; k < 8; ++k) {
        int i = base + k * 256 + tid;
        if (i < E) recs[rb[rec[k] >> 24] + rk[k]] = rec[k];
    }
}

// ---- level B: one block per bucket. row_ptr+dinv coalesced; final u16
// edge scatter stays inside this block's 8KB region (no cross-XCD bounce).
__global__ __launch_bounds__(256) void k_phaseB(
        const uint* __restrict__ recs, const int* __restrict__ bbase,
        int* __restrict__ row_ptr, float* __restrict__ dinv,
        ushort* __restrict__ edges, int N, int E, int NBUCK) {
    __shared__ int h[256];
    __shared__ int p[256];
    const int tid = threadIdx.x;
    const int b = blockIdx.x;
    const int base = bbase[b];
    const int cnt  = bbase[b + 1] - base;
    h[tid] = 0;
    __syncthreads();
    for (int i = tid; i < cnt; i += 256)
        atomicAdd(&h[(recs[base + i] >> 16) & 255], 1);
    __syncthreads();
    int v = h[tid];
    p[tid] = v;
    __syncthreads();
    #pragma unroll
    for (int off = 1; off < 256; off <<= 1) {
        int x = (tid >= off) ? p[tid - off] : 0;
        __syncthreads();
        p[tid] += x;
        __syncthreads();
    }
    const int excl = p[tid] - v;
    const int node = b * 256 + tid;
    if (node < N) {
        row_ptr[node] = base + excl;
        dinv[node] = rsqrtf((float)(v + 1));
    }
    if (b == NBUCK - 1 && tid == 0) row_ptr[N] = E;
    h[tid] = excl;                     // reuse as local cursor
    __syncthreads();
    for (int i = tid; i < cnt; i += 256) {
        uint r = recs[base + i];
        int dl = (r >> 16) & 255;
        int pos = atomicAdd(&h[dl], 1);
        edges[base + pos] = (ushort)(r & 0xffffu);
    }
}

// ---- MFMA gemm with dinv-prescale epilogue: hp = dinv[row]*(x@W1) ----
__global__ __launch_bounds__(256, 4) void k_gemm(
        const float* __restrict__ x, const float* __restrict__ W1,
        const float* __restrict__ dinv, ushort* __restrict__ hp, int N) {
    const int tid = threadIdx.x;
    const int w = tid >> 6, l = tid & 63;
    const int m = l & 15, q = l >> 4;              // q = quad (0..3)
    const int row0 = blockIdx.x * 64 + w * 16;
    const size_t arow = (size_t)min(row0 + m, N - 1);   // clamp; store guarded
    f32x4 acc0 = {0.f, 0.f, 0.f, 0.f}, acc1 = acc0, acc2 = acc0, acc3 = acc0;
    #pragma unroll
    for (int kc = 0; kc < 4; ++kc) {
        const int kofs = kc * 32 + q * 8;
        const float4* xr = (const float4*)(x + arow * 128 + kofs);
        float4 xa = xr[0], xb = xr[1];
        short8 a;
        a[0] = (short)f2bf(xa.x); a[1] = (short)f2bf(xa.y);
        a[2] = (short)f2bf(xa.z); a[3] = (short)f2bf(xa.w);
        a[4] = (short)f2bf(xb.x); a[5] = (short)f2bf(xb.y);
        a[6] = (short)f2bf(xb.z); a[7] = (short)f2bf(xb.w);
        short8 b0, b1, b2, b3;                     // W1 L1-hot (32 KB)
        #pragma unroll
        for (int i = 0; i < 8; ++i) {
            const float* wk = W1 + (size_t)(kofs + i) * 64 + m;
            b0[i] = (short)f2bf(wk[0]);
            b1[i] = (short)f2bf(wk[16]);
            b2[i] = (short)f2bf(wk[32]);
            b3[i] = (short)f2bf(wk[48]);
        }
        acc0 = __builtin_amdgcn_mfma_f32_16x16x32_bf16(a, b0, acc0, 0, 0, 0);
        acc1 = __builtin_amdgcn_mfma_f32_16x16x32_bf16(a, b1, acc1, 0, 0, 0);
        acc2 = __builtin_amdgcn_mfma_f32_16x16x32_bf16(a, b2, acc2, 0, 0, 0);
        acc3 = __builtin_amdgcn_mfma_f32_16x16x32_bf16(a, b3, acc3, 0, 0, 0);
    }
    #pragma unroll
    for (int r = 0; r < 4; ++r) {                  // D: row=q*4+r, col=g*16+m
        int row = row0 + q * 4 + r;
        if (row >= N) continue;
        float dv = dinv[row];
        ushort* hr = hp + (size_t)row * 64 + m;
        hr[0]  = f2bf(acc0[r] * dv);
        hr[16] = f2bf(acc1[r] * dv);
        hr[32] = f2bf(acc2[r] * dv);
        hr[48] = f2bf(acc3[r] * dv);
    }
}

// Norm-free gather over 64-feature rows (32 uints). Half-wave per edge:
// hl = lane&31 (feature pair), half = lane>>5 (edge parity). 2 edges/step,
// 8-step unroll = 16 row-loads in flight. Pure pk-adds. Butterfly at end.
__device__ __forceinline__ f32v2 gather_rows(
        const uint* __restrict__ hp, const ushort* __restrict__ edges,
        int beg, int end, int E, int lane, int hl, int half) {
    f32v2 acc = {0.f, 0.f};
    for (int base = beg; base < end; base += 64) {
        int cnt = end - base; if (cnt > 64) cnt = 64;
        int mrec = (int)edges[min(base + lane, E - 1)];   // coalesced 2B/lane
        int steps = (cnt + 1) >> 1;
        for (int t = 0; t < steps; t += 8) {
            if (2 * t + 16 <= cnt) {       // edges 2t..2t+15 all valid
                #pragma unroll
                for (int i = 0; i < 8; ++i) {
                    int r = __shfl(mrec, 2 * (t + i) + half);
                    uint v = hp[(size_t)r * 32 + hl];
                    f32v2 vf;
                    vf.x = __uint_as_float(v << 16);
                    vf.y = __uint_as_float(v & 0xffff0000u);
                    acc = acc + vf;
                }
            } else {
                #pragma unroll
                for (int i = 0; i < 8; ++i) {
                    int e = 2 * (t + i) + half;
                    int r = __shfl(mrec, min(e, cnt - 1));
                    uint v = hp[(size_t)r * 32 + hl];
                    v = (e < cnt) ? v : 0u;
                    f32v2 vf;
                    vf.x = __uint_as_float(v << 16);
                    vf.y = __uint_as_float(v & 0xffff0000u);
                    acc = acc + vf;
                }
            }
        }
    }
    acc.x += __shfl_xor(acc.x, 32);
    acc.y += __shfl_xor(acc.y, 32);
    return acc;
}

// hm[n] = dinv * relu( dinv * (sum hp[src] + hp[n]) + b1 )   (bf16x2)
__global__ __launch_bounds__(256, 8) void k_gather1(
        const uint* __restrict__ hp, const int* __restrict__ row_ptr,
        const ushort* __restrict__ edges, const float* __restrict__ dinv,
        const float* __restrict__ b1, uint* __restrict__ ho, int N, int E) {
    const int lane = threadIdx.x & 63;
    const int hl = lane & 31, half = lane >> 5;
    const int n = blockIdx.x * 4 + (threadIdx.x >> 6);
    if (n >= N) return;
    const int beg = row_ptr[n], end = row_ptr[n + 1];
    f32v2 acc = gather_rows(hp, edges, beg, end, E, lane, hl, half);
    if (half == 0) {
        const float dv = dinv[n];
        const uint sv = hp[(size_t)n * 32 + hl];       // self (pre-scaled)
        const float2 b = ((const float2*)b1)[hl];
        float s0 = acc.x + bf2f((ushort)sv);
        float s1 = acc.y + bf2f((ushort)(sv >> 16));
        float h0 = fmaxf(fmaf(dv, s0, b.x), 0.f) * dv; // relu then pre-scale
        float h1 = fmaxf(fmaf(dv, s1, b.y), 0.f) * dv;
        ho[(size_t)n * 32 + hl] = (uint)f2bf(h0) | ((uint)f2bf(h1) << 16);
    }
}

// g = dinv*(sum hm[src] + hm[n]);  out[n] = g @ [Wmu|Wls] + bias
__global__ __launch_bounds__(256, 8) void k_gather2(
        const uint* __restrict__ hp, const int* __restrict__ row_ptr,
        const ushort* __restrict__ edges, const float* __restrict__ dinv,
        const float* __restrict__ Wmu, const float* __restrict__ Wls,
        const float* __restrict__ bmu, const float* __restrict__ bls,
        float* __restrict__ out, int N, int E) {
    __shared__ float hs[4][64];    // per-wave g row (1 KB)
    const int lane = threadIdx.x & 63;
    const int hl = lane & 31, half = lane >> 5;
    const int w = threadIdx.x >> 6;
    const int n = blockIdx.x * 4 + w;
    if (n >= N) return;
    const int beg = row_ptr[n], end = row_ptr[n + 1];
    f32v2 acc = gather_rows(hp, edges, beg, end, E, lane, hl, half);
    if (half == 0) {
        const float dv = dinv[n];
        const uint sv = hp[(size_t)n * 32 + hl];
        float g0 = dv * (acc.x + bf2f((ushort)sv));
        float g1 = dv * (acc.y + bf2f((ushort)(sv >> 16)));
        float2 p; p.x = g0; p.y = g1;
        *(float2*)&hs[w][2 * hl] = p;
    }
    // epilogue: out_row = g @ [Wmu|Wls] + bias ; W from global (L1-hot)
    const float* Wsel = (lane < 32) ? (Wmu + lane) : (Wls + (lane - 32));
    const float bias  = (lane < 32) ? bmu[lane] : bls[lane - 32];
    float c0 = 0.f, c1 = 0.f, c2 = 0.f, c3 = 0.f;
    #pragma unroll 4
    for (int k = 0; k < 64; k += 4) {
        c0 = fmaf(hs[w][k + 0], Wsel[(k + 0) * 32], c0);
        c1 = fmaf(hs[w][k + 1], Wsel[(k + 1) * 32], c1);
        c2 = fmaf(hs[w][k + 2], Wsel[(k + 2) * 32], c2);
        c3 = fmaf(hs[w][k + 3], Wsel[(k + 3) * 32], c3);
    }
    float t = (c0 + c1) + (c2 + c3) + bias;
    if (lane < 32) out[(size_t)n * 32 + lane] = t;
    else           out[(size_t)N * 32 + (size_t)n * 32 + (lane - 32)] = t;
}

extern "C" void kernel_launch(void* const* d_in, const int* in_sizes, int n_in,
                              void* d_out, int out_size, void* d_ws, size_t ws_size,
                              hipStream_t stream) {
    const float* x   = (const float*)d_in[0];
    const int*   ei  = (const int*)d_in[1];
    const float* W1  = (const float*)d_in[2];
    const float* b1  = (const float*)d_in[3];
    const float* Wmu = (const float*)d_in[4];
    const float* bmu = (const float*)d_in[5];
    const float* Wls = (const float*)d_in[6];
    const float* bls = (const float*)d_in[7];
    float* out = (float*)d_out;

    const int N = in_sizes[0] / 128;          // 50000  (< 65536: u16 src pack)
    const int E = in_sizes[1] / 2;            // 800000
    const int* src = ei;
    const int* dst = ei + E;
    const int HB    = (E + 2047) / 2048;      // hist/scatterA blocks (391)
    const int NBUCK = (N + 255) / 256;        // coarse buckets (196)
    const int GB    = (N + 63) / 64;          // gemm row-tile blocks
    const int NG    = (N + 3) / 4;            // gather blocks

    char* w = (char*)d_ws;
    auto carve = [&](size_t bytes) { char* p = w; w += (bytes + 1023) & ~(size_t)1023; return p; };
    int*    bcount  = (int*)   carve(256 * 4);
    int*    bbase   = (int*)   carve(257 * 4);
    int*    bcursor = (int*)   carve(256 * 4);
    uint*   recs    = (uint*)  carve((size_t)E * 4);        // level-A records
    int*    row_ptr = (int*)   carve((size_t)(N + 1) * 4);
    float*  dinv    = (float*) carve((size_t)N * 4);
    ushort* edges   = (ushort*)carve((size_t)E * 2);        // u16 src records
    ushort* h_pre   = (ushort*)carve((size_t)N * 64 * 2);   // bf16 (pre-scaled)
    ushort* h_mid   = (ushort*)carve((size_t)N * 64 * 2);   // bf16 (pre-scaled)

    hipMemsetAsync(bcount, 0, 256 * 4, stream);
    k_hist    <<<HB, 256, 0, stream>>>(dst, bcount, E);
    k_bscan   <<<1, 256, 0, stream>>>(bcount, bbase, bcursor, E);
    k_scatterA<<<HB, 256, 0, stream>>>(src, dst, bcursor, recs, E);
    k_phaseB  <<<NBUCK, 256, 0, stream>>>(recs, bbase, row_ptr, dinv, edges, N, E, NBUCK);
    k_gemm    <<<GB, 256, 0, stream>>>(x, W1, dinv, h_pre, N);
    k_gather1 <<<NG, 256, 0, stream>>>((const uint*)h_pre, row_ptr, edges, dinv,
                                       b1, (uint*)h_mid, N, E);
    k_gather2 <<<NG, 256, 0, stream>>>((const uint*)h_mid, row_ptr, edges, dinv,
                                       Wmu, Wls, bmu, bls, out, N, E);
}